// Round 4
// baseline (862.743 us; speedup 1.0000x reference)
//
#include <hip/hip_runtime.h>
#include <math.h>

typedef _Float16 h2_t __attribute__((ext_vector_type(2)));
typedef _Float16 h8_t __attribute__((ext_vector_type(8)));

#define NP 32
#define KC 31
#define HH 512
#define WW 512
#define BB 4
#define CC 3

#define TXO 32
#define TYO 32
#define TROWS 62      // 32 output rows + 15+15 halo
#define TSTR 48       // words per tile row (stride%32==16 -> 2-way-free b128 reads)
#define TLW 36        // logical words staged per row (words 0..33 used, pad to mult-4)
#define WSTR 36       // weight table plane stride in h2 words: A[0..15] B[16..31] pad[32..35]

__device__ __forceinline__ double plane_of(int i) {
    const double stepd = 50.0 / 31.0;
    return (i < 31) ? (double)i * stepd : 50.0;
}

// One block = one (batch, channel, 32x32 tile). Weights computed in-block.
__launch_bounds__(256, 2)
__global__ void defocus_kernel(const float* __restrict__ img,
                               const float* __restrict__ coc,
                               float* __restrict__ out) {
    const int tx = threadIdx.x;            // 0..7
    const int ty = threadIdx.y;            // 0..31
    const int tid = ty * 8 + tx;
    const int tilex = blockIdx.x * TXO;
    const int tiley = blockIdx.y * TYO;
    const int bc = blockIdx.z;             // b*CC + c
    const int b = bc / CC;
    const int c = bc - b * CC;

    __shared__ __align__(16) h2_t tileA[TROWS * TSTR];
    __shared__ __align__(16) h2_t tileB[TROWS * TSTR];   // logical words shifted by +2
    __shared__ __align__(16) h2_t wtab[NP * WSTR];

    // ---- phase 1: per-plane Gaussian taps (f32) into scratch (overlays tileA) ----
    float* tapsf = (float*)tileA;          // 32 planes x 32 taps = 4 KB
    {
        const int t = tid & 31;            // tap slot 0..31 (g[31] stays 0)
        const int pg = tid >> 5;           // plane group 0..7
        #pragma unroll
        for (int k = 0; k < 4; ++k) {
            const int p = pg + 8 * k;
            const double stepd = 50.0 / 31.0;
            double coco = (p < 31) ? (double)p * stepd : 50.0;  // numpy linspace
            float gt;
            if (coco < 0.5) {
                gt = (t == 15) ? 1.f : 0.f;           // identity plane
            } else {
                double sigma = coco / 2.355;
                int kk = (int)(2.0 * coco + 1.0);     // trunc, matches python int()
                if ((kk & 1) == 0) kk += 1;
                if (kk > KC) kk = KC;
                int h = kk / 2;
                int d = t - 15;
                float denom = (float)(2.0 * sigma * sigma);
                float v = (d >= -h && d <= h && t < KC) ? expf(-(float)(d * d) / denom) : 0.f;
                float s = v;
                #pragma unroll
                for (int off = 1; off < 32; off <<= 1) s += __shfl_xor(s, off, 32);
                gt = v / s;
            }
            tapsf[p * 32 + t] = gt;
        }
    }

    // ---- per-pixel bin index (independent of LDS phases) ----
    const int yo = tiley + ty;
    const int xo = tilex + tx * 4;
    const float4 cv = *(const float4*)&coc[((size_t)b * HH + yo) * WW + xo];
    const float cocf[4] = {cv.x, cv.y, cv.z, cv.w};
    int idx[4];
    #pragma unroll
    for (int j = 0; j < 4; ++j) {
        const double stepd = 50.0 / 31.0;
        double cd = (double)cocf[j];
        int i0 = (int)floor(cd / stepd + 0.5);
        i0 = min(max(i0, 0), 31);
        if (i0 > 0 && cd <= 0.5 * (plane_of(i0 - 1) + plane_of(i0))) {
            i0 -= 1;
        } else if (i0 < 31 && cd > 0.5 * (plane_of(i0) + plane_of(i0 + 1))) {
            i0 += 1;
        }
        idx[j] = i0;
    }

    __syncthreads();  // taps ready

    // ---- phase 2: pack wtab: A[m]=(g[2m],g[2m+1]) at +0, B[m]=(g[2m-1],g[2m]) at +16 ----
    for (int f = tid; f < NP * WSTR; f += 256) {
        const int p = f / WSTR;
        const int m = f - p * WSTR;
        float lo = 0.f, hi = 0.f;
        if (m < 16) {
            lo = tapsf[p * 32 + 2 * m];
            hi = tapsf[p * 32 + 2 * m + 1];
        } else if (m < 32) {
            const int mm = m - 16;
            lo = (2 * mm - 1 >= 0) ? tapsf[p * 32 + 2 * mm - 1] : 0.f;
            hi = tapsf[p * 32 + 2 * mm];
        }
        h2_t w; w.x = (_Float16)lo; w.y = (_Float16)hi;
        wtab[f] = w;
    }
    __syncthreads();  // wtab ready (tapsf dead)

    // ---- gather weight rows to registers ----
    // tile origin x = tilex-16 => output j's window starts at local half j+1:
    //   j=0: phase B, word +0   j=1: phase A, word +1
    //   j=2: phase B, word +1   j=3: phase A, word +2
    h2_t wj[4][16];
    #pragma unroll
    for (int j = 0; j < 4; ++j) {
        const h2_t* wp = &wtab[idx[j] * WSTR + ((j & 1) ? 0 : 16)];  // odd j: A, even j: B
        #pragma unroll
        for (int m = 0; m < 4; ++m) {
            h8_t v = *(const h8_t*)(wp + 4 * m);   // 16B aligned
            #pragma unroll
            for (int q = 0; q < 4; ++q) {
                h2_t t; t.x = v[2 * q]; t.y = v[2 * q + 1];
                wj[j][4 * m + q] = t;
            }
        }
    }
    __syncthreads();  // all gathers done before tileA is overwritten

    // ---- stage tile (one channel), dual copies: tileB[u] = logical[u+2] ----
    {
        const float* src = img + (size_t)(b * CC + c) * HH * WW;
        for (int f = tid; f < TROWS * TLW; f += 256) {
            const int r = f / TLW;
            const int w = f - r * TLW;
            const int gy = tiley - 15 + r;
            const int gx = tilex - 16 + 2 * w;   // even -> float2 is 8B aligned
            float v0 = 0.f, v1 = 0.f;
            if ((unsigned)gy < (unsigned)HH && (unsigned)gx < (unsigned)WW) {
                const float2 fv = *(const float2*)&src[gy * WW + gx];
                v0 = fv.x; v1 = fv.y;            // gx even & <512 => gx+1 also in-bounds
            }
            h2_t pv; pv.x = (_Float16)v0; pv.y = (_Float16)v1;
            tileA[r * TSTR + w] = pv;
            if (w >= 2) tileB[r * TSTR + w - 2] = pv;
        }
    }
    __syncthreads();

    // ---- main loop: 31 rows x (5 ds_read_b128 + 64 fdot2) ----
    const int par = tx & 1;
    const h2_t* rowbase = par ? &tileB[ty * TSTR + 2 * tx - 2]
                              : &tileA[ty * TSTR + 2 * tx];   // word%4==0 both ways

    float acc0 = 0.f, acc1 = 0.f, acc2 = 0.f, acc3 = 0.f;
    #pragma unroll
    for (int dy = 0; dy < KC; ++dy) {
        const h2_t* rp = rowbase + dy * TSTR;
        h2_t rw[20];
        #pragma unroll
        for (int m = 0; m < 5; ++m) {
            h8_t q = *(const h8_t*)(rp + 4 * m);   // ds_read_b128, 2-way-free banks
            #pragma unroll
            for (int qq = 0; qq < 4; ++qq) {
                h2_t t; t.x = q[2 * qq]; t.y = q[2 * qq + 1];
                rw[4 * m + qq] = t;
            }
        }
        float rs0 = 0.f, rs1 = 0.f, rs2 = 0.f, rs3 = 0.f;
        #pragma unroll
        for (int m = 0; m < 16; ++m) {
            rs0 = __builtin_amdgcn_fdot2(wj[0][m], rw[m],     rs0, false);
            rs1 = __builtin_amdgcn_fdot2(wj[1][m], rw[m + 1], rs1, false);
            rs2 = __builtin_amdgcn_fdot2(wj[2][m], rw[m + 1], rs2, false);
            rs3 = __builtin_amdgcn_fdot2(wj[3][m], rw[m + 2], rs3, false);
        }
        // column taps g[dy] extracted at static indices:
        // phase B (j even): g[2m-1]=B[m].x, g[2m]=B[m].y ; phase A (j odd): g[2m]=A[m].x, g[2m+1]=A[m].y
        float cw0, cw1, cw2, cw3;
        if ((dy & 1) == 0) {
            cw0 = (float)wj[0][dy >> 1].y;
            cw2 = (float)wj[2][dy >> 1].y;
            cw1 = (float)wj[1][dy >> 1].x;
            cw3 = (float)wj[3][dy >> 1].x;
        } else {
            cw0 = (float)wj[0][(dy + 1) >> 1].x;
            cw2 = (float)wj[2][(dy + 1) >> 1].x;
            cw1 = (float)wj[1][dy >> 1].y;
            cw3 = (float)wj[3][dy >> 1].y;
        }
        acc0 += cw0 * rs0;
        acc1 += cw1 * rs1;
        acc2 += cw2 * rs2;
        acc3 += cw3 * rs3;
    }

    *(float4*)&out[((size_t)(b * CC + c) * HH + yo) * WW + xo] =
        make_float4(acc0, acc1, acc2, acc3);
}

extern "C" void kernel_launch(void* const* d_in, const int* in_sizes, int n_in,
                              void* d_out, int out_size, void* d_ws, size_t ws_size,
                              hipStream_t stream) {
    const float* sharp = (const float*)d_in[0];
    const float* cocm  = (const float*)d_in[1];
    float* out = (float*)d_out;

    dim3 grid(WW / TXO, HH / TYO, BB * CC);
    dim3 block(8, 32, 1);
    defocus_kernel<<<grid, block, 0, stream>>>(sharp, cocm, out);
}

// Round 5
// 564.366 us; speedup vs baseline: 1.5287x; 1.5287x over previous
//
#include <hip/hip_runtime.h>
#include <math.h>

typedef _Float16 h2_t __attribute__((ext_vector_type(2)));
typedef _Float16 h4_t __attribute__((ext_vector_type(4)));
typedef _Float16 h8_t __attribute__((ext_vector_type(8)));

#define NP 32
#define KC 31
#define HH 512
#define WW 512
#define BB 4
#define CC 3

#define TXO 32
#define TYO 32
#define TROWS 62      // 32 output rows + 15+15 halo
#define TWORDS 48     // tile row stride in h2 words (%32==16 -> conflict-free pattern)
#define TLW 32        // words actually staged per row (reads touch words 0..31 only)
#define WSTR 36       // weight plane stride in h2 words: A[0..15] B[16..31] pad[32..35]

// Packed per-plane taps: A[m]=(g[2m],g[2m+1]), B[m]=(g[2m-1],g[2m]).
// Kept in a separate init kernel: folding the double-precision weight gen into
// the hot kernel (R4) overlapped its transient pressure with wj[4][16] and the
// allocator spilled the dy-loop state (WRITE_SIZE 1.57 GB, 822 us). Do not inline.
__device__ h2_t g_wtabh[NP * WSTR];

__global__ void init_wtab_kernel() {
    const int tid = threadIdx.x;          // 0..1023
    const int p = tid >> 5;               // plane
    const int t = tid & 31;               // padded tap 0..31 (g[31]==0)
    const double stepd = 50.0 / 31.0;
    double coc = (p < 31) ? (double)p * stepd : 50.0;   // numpy linspace semantics
    float gt;
    if (coc < 0.5) {
        gt = (t == 15) ? 1.f : 0.f;       // identity plane
    } else {
        double sigma = coc / 2.355;
        int k = (int)(2.0 * coc + 1.0);   // trunc, matches python int()
        if ((k & 1) == 0) k += 1;
        if (k > KC) k = KC;
        int h = k / 2;
        int d = t - 15;
        float denom = (float)(2.0 * sigma * sigma);
        float v = (d >= -h && d <= h && t < KC) ? expf(-(float)(d * d) / denom) : 0.f;
        float s = v;
        #pragma unroll
        for (int off = 1; off < 32; off <<= 1) s += __shfl_xor(s, off, 32);
        gt = v / s;
    }
    const int m = t & 15;
    const int s0 = (t < 16) ? (2 * m) : ((2 * m - 1 < 0) ? 0 : 2 * m - 1);
    const int s1 = (t < 16) ? (2 * m + 1) : (2 * m);
    float w0 = __shfl(gt, s0, 32);
    float w1 = __shfl(gt, s1, 32);
    if (t >= 16 && (2 * m - 1) < 0) w0 = 0.f;   // g[-1] = 0
    h2_t w; w.x = (_Float16)w0; w.y = (_Float16)w1;
    g_wtabh[p * WSTR + t] = w;
    if (t < WSTR - 32) {
        h2_t z; z.x = (_Float16)0.f; z.y = (_Float16)0.f;
        g_wtabh[p * WSTR + 32 + t] = z;
    }
}

__device__ __forceinline__ double plane_of(int i) {
    const double stepd = 50.0 / 31.0;
    return (i < 31) ? (double)i * stepd : 50.0;
}

// One block = one (batch, channel, 32x32 tile). 3072 blocks -> staging of one
// block overlaps compute of others; single barrier.
__launch_bounds__(256, 2)
__global__ void defocus_kernel(const float* __restrict__ img,
                               const float* __restrict__ coc,
                               float* __restrict__ out) {
    const int tx = threadIdx.x;            // 0..7
    const int ty = threadIdx.y;            // 0..31
    const int tid = ty * 8 + tx;
    const int tilex = blockIdx.x * TXO;
    const int tiley = blockIdx.y * TYO;
    const int bc = blockIdx.z;             // b*CC + c
    const int b = bc / CC;

    __shared__ __align__(16) h2_t wtab[NP * WSTR];
    __shared__ __align__(16) h2_t tile[TROWS * TWORDS];

    // stage weight table (global -> LDS)
    for (int f = tid; f < NP * WSTR; f += 256) wtab[f] = g_wtabh[f];

    // stage image tile for this (b,c): 62 rows x 32 words, origin (tiley-15, tilex-15)
    {
        const float* src = img + (size_t)bc * HH * WW;
        for (int f = tid; f < TROWS * TLW; f += 256) {
            const int r = f >> 5;          // /TLW
            const int w = f & 31;
            const int gy = tiley - 15 + r;
            const int gx = tilex - 15 + 2 * w;
            float v0 = 0.f, v1 = 0.f;
            if ((unsigned)gy < (unsigned)HH) {
                if ((unsigned)gx < (unsigned)WW) v0 = src[gy * WW + gx];
                if ((unsigned)(gx + 1) < (unsigned)WW) v1 = src[gy * WW + gx + 1];
            }
            h2_t pv; pv.x = (_Float16)v0; pv.y = (_Float16)v1;
            tile[r * TWORDS + w] = pv;
        }
    }

    // per-pixel bin index, exact double-precision boundary semantics
    const int yo = tiley + ty;
    const int xo = tilex + tx * 4;
    const float4 cv = *(const float4*)&coc[((size_t)b * HH + yo) * WW + xo];
    const float cocf[4] = {cv.x, cv.y, cv.z, cv.w};
    int idx[4];
    #pragma unroll
    for (int j = 0; j < 4; ++j) {
        const double stepd = 50.0 / 31.0;
        double cd = (double)cocf[j];
        int i0 = (int)floor(cd / stepd + 0.5);
        i0 = min(max(i0, 0), 31);
        if (i0 > 0 && cd <= 0.5 * (plane_of(i0 - 1) + plane_of(i0))) {
            i0 -= 1;
        } else if (i0 < 31 && cd > 0.5 * (plane_of(i0) + plane_of(i0 + 1))) {
            i0 += 1;
        }
        idx[j] = i0;
    }

    __syncthreads();  // wtab + tile staged

    // gather weight rows to registers: even j -> phase A, odd j -> phase B
    h2_t wj[4][16];
    #pragma unroll
    for (int j = 0; j < 4; ++j) {
        const h2_t* wp = &wtab[idx[j] * WSTR + (j & 1) * 16];
        #pragma unroll
        for (int m = 0; m < 4; ++m) {
            h8_t v = *(const h8_t*)(wp + 4 * m);   // 16B aligned: WSTR%4==0
            #pragma unroll
            for (int q = 0; q < 4; ++q) {
                h2_t t; t.x = v[2 * q]; t.y = v[2 * q + 1];
                wj[j][4 * m + q] = t;
            }
        }
    }

    float acc0 = 0.f, acc1 = 0.f, acc2 = 0.f, acc3 = 0.f;
    const h2_t* rowbase = &tile[ty * TWORDS + 2 * tx];
    #pragma unroll
    for (int dy = 0; dy < KC; ++dy) {
        const h2_t* rp = rowbase + dy * TWORDS;
        h2_t rw[18];
        #pragma unroll
        for (int m = 0; m < 9; ++m) {
            h4_t q = *(const h4_t*)(rp + 2 * m);   // ds_read_b64, conflict-free layout
            h2_t lo; lo.x = q[0]; lo.y = q[1];
            h2_t hi; hi.x = q[2]; hi.y = q[3];
            rw[2 * m]     = lo;
            rw[2 * m + 1] = hi;
        }
        float rs0 = 0.f, rs1 = 0.f, rs2 = 0.f, rs3 = 0.f;
        #pragma unroll
        for (int m = 0; m < 16; ++m) {
            rs0 = __builtin_amdgcn_fdot2(wj[0][m], rw[m],     rs0, false);
            rs1 = __builtin_amdgcn_fdot2(wj[1][m], rw[m],     rs1, false);
            rs2 = __builtin_amdgcn_fdot2(wj[2][m], rw[m + 1], rs2, false);
            rs3 = __builtin_amdgcn_fdot2(wj[3][m], rw[m + 1], rs3, false);
        }
        // column taps g[dy] at static register indices
        float cw0, cw1, cw2, cw3;
        if ((dy & 1) == 0) {
            cw0 = (float)wj[0][dy >> 1].x;           // A: lo = g[dy]
            cw2 = (float)wj[2][dy >> 1].x;
            cw1 = (float)wj[1][dy >> 1].y;           // B: hi = g[dy]
            cw3 = (float)wj[3][dy >> 1].y;
        } else {
            cw0 = (float)wj[0][dy >> 1].y;           // A: hi = g[dy]
            cw2 = (float)wj[2][dy >> 1].y;
            cw1 = (float)wj[1][(dy + 1) >> 1].x;     // B: lo of next word = g[dy]
            cw3 = (float)wj[3][(dy + 1) >> 1].x;
        }
        acc0 += cw0 * rs0;
        acc1 += cw1 * rs1;
        acc2 += cw2 * rs2;
        acc3 += cw3 * rs3;
    }

    *(float4*)&out[((size_t)bc * HH + yo) * WW + xo] =
        make_float4(acc0, acc1, acc2, acc3);
}

extern "C" void kernel_launch(void* const* d_in, const int* in_sizes, int n_in,
                              void* d_out, int out_size, void* d_ws, size_t ws_size,
                              hipStream_t stream) {
    const float* sharp = (const float*)d_in[0];
    const float* cocm  = (const float*)d_in[1];
    float* out = (float*)d_out;

    init_wtab_kernel<<<1, 1024, 0, stream>>>();
    dim3 grid(WW / TXO, HH / TYO, BB * CC);
    dim3 block(8, 32, 1);
    defocus_kernel<<<grid, block, 0, stream>>>(sharp, cocm, out);
}

// Round 6
// 138.810 us; speedup vs baseline: 6.2153x; 4.0657x over previous
//
#include <hip/hip_runtime.h>
#include <math.h>

typedef _Float16 h2_t __attribute__((ext_vector_type(2)));
typedef _Float16 h4_t __attribute__((ext_vector_type(4)));
typedef _Float16 h8_t __attribute__((ext_vector_type(8)));

#define NP 32
#define KC 31
#define HH 512
#define WW 512
#define BB 4
#define CC 3

#define TXO 32
#define TYO 32
#define TROWS 62      // 32 outputs + 15 + 15 halo
#define TWORDS 48     // tile row STRIDE in half2-words (%32==16 -> conflict-free)
#define TLW 32        // words STAGED per row (reads only touch words 0..31; R5-verified)
#define WSTR 36       // weight table plane stride in half2-words

// Packed per-plane 1D Gaussian taps, phase A = (g[2m],g[2m+1]), phase B = (g[2m-1],g[2m]).
// NOTE (R4/R5 evidence): keep weight generation in this separate kernel, keep the
// defocus grid at z=4 with the in-kernel channel loop. Both channel-split variants
// (z=12) produced ~1 GB of scratch-signature HBM traffic and 5x regressions.
__device__ h2_t g_wtabh[NP * WSTR];

// 32 planes x 32 lanes: one padded tap per lane, shfl-reduce the normalizer,
// shuffle-pack both phases. (~2 us)
__global__ void init_wtab_kernel() {
    const int tid = threadIdx.x;          // 0..1023
    const int p = tid >> 5;               // plane
    const int t = tid & 31;               // padded tap position 0..31 (g[31]==0)
    const double stepd = 50.0 / 31.0;
    double coc = (p < 31) ? (double)p * stepd : 50.0;   // numpy linspace semantics
    float gt;
    if (coc < 0.5) {
        gt = (t == 15) ? 1.f : 0.f;       // identity plane (plane 0 only)
    } else {
        double sigma = coc / 2.355;
        int k = (int)(2.0 * coc + 1.0);   // trunc, matches python int()
        if ((k & 1) == 0) k += 1;
        if (k > KC) k = KC;
        int h = k / 2;
        int d = t - 15;
        float denom = (float)(2.0 * sigma * sigma);
        float v = (d >= -h && d <= h && t < KC) ? expf(-(float)(d * d) / denom) : 0.f;
        float s = v;
        #pragma unroll
        for (int off = 1; off < 32; off <<= 1) s += __shfl_xor(s, off, 32);
        gt = v / s;
    }
    // pack: lanes 0..15 build phase-A word m=t: (g[2m], g[2m+1])
    //       lanes 16..31 build phase-B word m=t-16: (g[2m-1], g[2m])
    const int m = t & 15;
    const int s0 = (t < 16) ? (2 * m) : ((2 * m - 1 < 0) ? 0 : 2 * m - 1);
    const int s1 = (t < 16) ? (2 * m + 1) : (2 * m);
    float w0 = __shfl(gt, s0, 32);
    float w1 = __shfl(gt, s1, 32);
    if (t >= 16 && (2 * m - 1) < 0) w0 = 0.f;   // g[-1] = 0
    h2_t w; w.x = (_Float16)w0; w.y = (_Float16)w1;
    g_wtabh[p * WSTR + t] = w;
    if (t < WSTR - 32) {                  // zero the 4 pad words
        h2_t z; z.x = (_Float16)0.f; z.y = (_Float16)0.f;
        g_wtabh[p * WSTR + 32 + t] = z;
    }
}

__device__ __forceinline__ double plane_of(int i) {
    const double stepd = 50.0 / 31.0;
    return (i < 31) ? (double)i * stepd : 50.0;
}

// (256,2): 256-VGPR allocator cap. (256,4)'s 128 cap spilled wj[4][16] (R2:
// WRITE_SIZE 252 MB). Proven clean at 93 us with z=4 grid + in-kernel c-loop.
__launch_bounds__(256, 2)
__global__ void defocus_kernel(const float* __restrict__ img,
                               const float* __restrict__ coc,
                               float* __restrict__ out) {
    const int tx = threadIdx.x;            // 0..7
    const int ty = threadIdx.y;            // 0..31
    const int tid = ty * 8 + tx;
    const int tilex = blockIdx.x * TXO;
    const int tiley = blockIdx.y * TYO;
    const int b = blockIdx.z;

    __shared__ __align__(16) h2_t wtab[NP * WSTR];
    __shared__ __align__(16) h2_t tile[TROWS * TWORDS];

    for (int f = tid; f < NP * WSTR; f += 256) wtab[f] = g_wtabh[f];

    const int yo = tiley + ty;
    const int xo = tilex + tx * 4;

    // per-pixel bin index, exact double-precision boundary semantics
    const float4 cv = *(const float4*)&coc[((size_t)b * HH + yo) * WW + xo];
    const float cocf[4] = {cv.x, cv.y, cv.z, cv.w};
    int idx[4];
    #pragma unroll
    for (int j = 0; j < 4; ++j) {
        const double stepd = 50.0 / 31.0;
        double cd = (double)cocf[j];
        int i0 = (int)floor(cd / stepd + 0.5);
        i0 = min(max(i0, 0), 31);
        if (i0 > 0 && cd <= 0.5 * (plane_of(i0 - 1) + plane_of(i0))) {
            i0 -= 1;
        } else if (i0 < 31 && cd > 0.5 * (plane_of(i0) + plane_of(i0 + 1))) {
            i0 += 1;
        }
        idx[j] = i0;
    }

    __syncthreads();  // wtab staged

    // gather this thread's 4 weight rows into registers (one-time random-indexed reads)
    // even local col (j=0,2): phase A; odd (j=1,3): phase B (pre-shifted by one tap)
    h2_t wj[4][16];
    #pragma unroll
    for (int j = 0; j < 4; ++j) {
        const h2_t* wp = &wtab[idx[j] * WSTR + (j & 1) * 16];
        #pragma unroll
        for (int m = 0; m < 4; ++m) {
            h8_t v = *(const h8_t*)(wp + 4 * m);   // 16B aligned: WSTR%4==0
            #pragma unroll
            for (int q = 0; q < 4; ++q) {
                h2_t t; t.x = v[2 * q]; t.y = v[2 * q + 1];
                wj[j][4 * m + q] = t;
            }
        }
    }

    for (int c = 0; c < CC; ++c) {
        __syncthreads();  // previous channel's readers done
        const float* src = img + (size_t)(b * CC + c) * HH * WW;
        // stage only words 0..31 of each row (stride stays 48); R5 verified
        // words 32..47 are never read.
        for (int f = tid; f < TROWS * TLW; f += 256) {
            int r = f >> 5;            // / TLW
            int w = f & 31;            // % TLW
            int gy = tiley - 15 + r;
            int gx = tilex - 15 + 2 * w;
            float v0 = 0.f, v1 = 0.f;
            if ((unsigned)gy < (unsigned)HH) {
                if ((unsigned)gx < (unsigned)WW) v0 = src[gy * WW + gx];
                if ((unsigned)(gx + 1) < (unsigned)WW) v1 = src[gy * WW + gx + 1];
            }
            h2_t pv; pv.x = (_Float16)v0; pv.y = (_Float16)v1;
            tile[r * TWORDS + w] = pv;
        }
        __syncthreads();

        float acc0 = 0.f, acc1 = 0.f, acc2 = 0.f, acc3 = 0.f;
        const h2_t* rowbase = &tile[ty * TWORDS + 2 * tx];
        #pragma unroll
        for (int dy = 0; dy < KC; ++dy) {
            const h2_t* rp = rowbase + dy * TWORDS;
            h2_t rw[18];
            #pragma unroll
            for (int m = 0; m < 9; ++m) {
                h4_t q = *(const h4_t*)(rp + 2 * m);   // ds_read_b64, conflict-free layout
                h2_t lo; lo.x = q[0]; lo.y = q[1];
                h2_t hi; hi.x = q[2]; hi.y = q[3];
                rw[2 * m]     = lo;
                rw[2 * m + 1] = hi;
            }
            float rs0 = 0.f, rs1 = 0.f, rs2 = 0.f, rs3 = 0.f;
            #pragma unroll
            for (int m = 0; m < 16; ++m) {
                rs0 = __builtin_amdgcn_fdot2(wj[0][m], rw[m],     rs0, false);
                rs1 = __builtin_amdgcn_fdot2(wj[1][m], rw[m],     rs1, false);
                rs2 = __builtin_amdgcn_fdot2(wj[2][m], rw[m + 1], rs2, false);
                rs3 = __builtin_amdgcn_fdot2(wj[3][m], rw[m + 1], rs3, false);
            }
            // column taps g[dy] from the same registers (dy unrolled -> static indices)
            float cw0, cw1, cw2, cw3;
            if ((dy & 1) == 0) {
                cw0 = (float)wj[0][dy >> 1].x;           // A: lo = g[dy]
                cw2 = (float)wj[2][dy >> 1].x;
                cw1 = (float)wj[1][dy >> 1].y;           // B: hi = g[dy]
                cw3 = (float)wj[3][dy >> 1].y;
            } else {
                cw0 = (float)wj[0][dy >> 1].y;           // A: hi = g[dy]
                cw2 = (float)wj[2][dy >> 1].y;
                cw1 = (float)wj[1][(dy + 1) >> 1].x;     // B: lo of next word = g[dy]
                cw3 = (float)wj[3][(dy + 1) >> 1].x;
            }
            acc0 += cw0 * rs0;
            acc1 += cw1 * rs1;
            acc2 += cw2 * rs2;
            acc3 += cw3 * rs3;
        }

        *(float4*)&out[((size_t)(b * CC + c) * HH + yo) * WW + xo] =
            make_float4(acc0, acc1, acc2, acc3);
    }
}

extern "C" void kernel_launch(void* const* d_in, const int* in_sizes, int n_in,
                              void* d_out, int out_size, void* d_ws, size_t ws_size,
                              hipStream_t stream) {
    const float* sharp = (const float*)d_in[0];
    const float* cocm  = (const float*)d_in[1];
    float* out = (float*)d_out;

    init_wtab_kernel<<<1, 1024, 0, stream>>>();
    dim3 grid(WW / TXO, HH / TYO, BB);
    dim3 block(8, 32, 1);
    defocus_kernel<<<grid, block, 0, stream>>>(sharp, cocm, out);
}